// Round 2
// baseline (566.317 us; speedup 1.0000x reference)
//
#include <hip/hip_runtime.h>

// Bilinear backward warp, NCHW f32, LDS-tiled gather.
// Tile: 64x32 pixels per block, halo RAD=8 each side -> 80x48 f32 LDS tile
// (15360 B). 256 threads, 8 pixels/thread. Channel loop re-stages LDS with
// coalesced float4 loads; gathers hit LDS. Rare out-of-halo flow falls back
// to global loads (correctness path, ~never taken for N(0,1) flow).

#define TSX 64
#define TSY 32
#define RAD 8
#define LW  80   // TSX + 2*RAD
#define LH  48   // TSY + 2*RAD
#define NTHREADS 256

__global__ __launch_bounds__(NTHREADS) void warp_tiled(
    const float* __restrict__ img,
    const float* __restrict__ flow,
    const int* __restrict__ Hp,
    const int* __restrict__ Wp,
    float* __restrict__ out,
    int HW, int C)
{
    __shared__ __align__(16) float lds[LH * LW];

    const int W = *Wp;
    const int H = *Hp;
    const int tilesX = (W + TSX - 1) / TSX;
    const int tilesY = (H + TSY - 1) / TSY;
    const int bid = blockIdx.x;
    if (bid >= tilesX * tilesY) return;

    const int tx = bid % tilesX;
    const int ty = bid / tilesX;
    const int gx0 = tx * TSX - RAD;   // halo origin (may be negative)
    const int gy0 = ty * TSY - RAD;

    const int tid = threadIdx.x;
    const int px  = tid & 63;   // 0..63 column within tile
    const int rb  = tid >> 6;   // 0..3 row sub-block

    const int gx = tx * TSX + px;

    const float Wm1 = (float)(W - 1);
    const float Hm1 = (float)(H - 1);

    // ---- per-pixel precompute: weights + packed LDS offset ----
    float wA[8], wB[8], wC[8], wD[8];
    int   enc[8];   // la | dx<<12 | dy<<13 ; -1 = global fallback; -2 = skip
    const int rowbase = (ty * TSY + rb) * W + gx;   // pixel index for k=0
    const int W4 = 4 * W;

    #pragma unroll
    for (int k = 0; k < 8; ++k) {
        const int pyl = rb + 4 * k;          // 0..31 local row
        const int gy  = ty * TSY + pyl;
        if (gx >= W || gy >= H) { enc[k] = -2; wA[k]=wB[k]=wC[k]=wD[k]=0.0f; continue; }
        const int pix = rowbase + k * W4;
        const float u = flow[pix];
        const float v = flow[HW + pix];

        float x = (float)gx + u;
        float y = (float)gy + v;
        x = 2.0f * (x / Wm1 - 0.5f);
        y = 2.0f * (y / Hm1 - 0.5f);
        x = (x + 1.0f) * 0.5f * Wm1;
        y = (y + 1.0f) * 0.5f * Hm1;

        const float x0 = floorf(x), x1 = x0 + 1.0f;
        const float y0 = floorf(y), y1 = y0 + 1.0f;

        const int x0c = (int)fminf(fmaxf(x0, 0.0f), Wm1);
        const int x1c = (int)fminf(fmaxf(x1, 0.0f), Wm1);
        const int y0c = (int)fminf(fmaxf(y0, 0.0f), Hm1);
        const int y1c = (int)fminf(fmaxf(y1, 0.0f), Hm1);

        wA[k] = (x1 - x) * (y1 - y);
        wB[k] = (x1 - x) * (y - y0);
        wC[k] = (x - x0) * (y1 - y);
        wD[k] = (x - x0) * (y - y0);

        const int lx0 = x0c - gx0, lx1 = x1c - gx0;
        const int ly0 = y0c - gy0, ly1 = y1c - gy0;
        if (lx0 >= 0 && ly0 >= 0 && lx1 < LW && ly1 < LH) {
            enc[k] = (ly0 * LW + lx0) | ((lx1 - lx0) << 12) | ((ly1 - ly0) << 13);
        } else {
            enc[k] = -1;   // out-of-halo flow: rare global fallback
        }
    }

    const bool interior = (gx0 >= 0) && (gx0 + LW <= W) && ((W & 3) == 0);

    for (int c = 0; c < C; ++c) {
        const float* __restrict__ ic = img + (size_t)c * (size_t)HW;
        float* __restrict__ oc = out + (size_t)c * (size_t)HW;

        __syncthreads();   // previous channel's LDS reads done

        // ---- stage 80x48 tile into LDS ----
        if (interior) {
            #pragma unroll
            for (int i0 = 0; i0 < (LH * LW / 4); i0 += NTHREADS) {
                const int i = i0 + tid;
                if (i < (LH * LW / 4)) {
                    const int r = i / (LW / 4);       // row 0..47
                    const int g = i - r * (LW / 4);   // float4 group 0..19
                    int yy = gy0 + r;
                    yy = min(max(yy, 0), H - 1);
                    const float4 vv = *(const float4*)(ic + (size_t)yy * W + (gx0 + g * 4));
                    *(float4*)&lds[r * LW + g * 4] = vv;
                }
            }
        } else {
            for (int i = tid; i < LH * LW; i += NTHREADS) {
                const int r = i / LW;
                const int cc = i - r * LW;
                const int yy = min(max(gy0 + r, 0), H - 1);
                const int xx = min(max(gx0 + cc, 0), W - 1);
                lds[i] = ic[(size_t)yy * W + xx];
            }
        }

        __syncthreads();

        // ---- gather + blend ----
        #pragma unroll
        for (int k = 0; k < 8; ++k) {
            const int e = enc[k];
            if (e == -2) continue;
            float Ia, Ib, Ic, Id;
            if (__builtin_expect(e >= 0, 1)) {
                const int la  = e & 4095;
                const int dx  = (e >> 12) & 1;
                const int dyo = ((e >> 13) & 1) * LW;
                Ia = lds[la];
                Ic = lds[la + dx];
                Ib = lds[la + dyo];
                Id = lds[la + dyo + dx];
            } else {
                // out-of-halo: recompute coords, gather from global
                const int pix = rowbase + k * W4;
                const int gy  = ty * TSY + rb + 4 * k;
                const float u = flow[pix];
                const float v = flow[HW + pix];
                float x = (float)gx + u;
                float y = (float)gy + v;
                x = 2.0f * (x / Wm1 - 0.5f);
                y = 2.0f * (y / Hm1 - 0.5f);
                x = (x + 1.0f) * 0.5f * Wm1;
                y = (y + 1.0f) * 0.5f * Hm1;
                const float x0 = floorf(x), y0 = floorf(y);
                const int x0c = (int)fminf(fmaxf(x0, 0.0f), Wm1);
                const int x1c = (int)fminf(fmaxf(x0 + 1.0f, 0.0f), Wm1);
                const int y0c = (int)fminf(fmaxf(y0, 0.0f), Hm1);
                const int y1c = (int)fminf(fmaxf(y0 + 1.0f, 0.0f), Hm1);
                Ia = ic[(size_t)y0c * W + x0c];
                Ib = ic[(size_t)y1c * W + x0c];
                Ic = ic[(size_t)y0c * W + x1c];
                Id = ic[(size_t)y1c * W + x1c];
            }
            oc[rowbase + k * W4] = wA[k] * Ia + wB[k] * Ib + wC[k] * Ic + wD[k] * Id;
        }
    }
}

extern "C" void kernel_launch(void* const* d_in, const int* in_sizes, int n_in,
                              void* d_out, int out_size, void* d_ws, size_t ws_size,
                              hipStream_t stream) {
    const float* img  = (const float*)d_in[0];
    const float* flow = (const float*)d_in[1];
    const int*   Hp   = (const int*)d_in[2];
    const int*   Wp   = (const int*)d_in[3];
    float* out = (float*)d_out;

    const int HW = in_sizes[1] / 2;    // flow is (1,2,H,W)
    const int C  = in_sizes[0] / HW;   // img is (1,C,H,W)

    const int tiles = (HW + TSX * TSY - 1) / (TSX * TSY);
    const int grid  = tiles + 64;      // slack for ragged tiling; excess blocks exit
    warp_tiled<<<grid, NTHREADS, 0, stream>>>(img, flow, Hp, Wp, out, HW, C);
}

// Round 3
// 219.487 us; speedup vs baseline: 2.5802x; 2.5802x over previous
//
#include <hip/hip_runtime.h>

// Bilinear backward warp, NCHW f32 — direct gather with PAIRED corner loads.
// Per pixel: the two x-corners (x0c, x0c+1) are loaded as ONE unaligned
// 8-byte load per row (top/bottom), halving scattered-gather instructions.
// Edge clamps are folded into precomputed lo/hi weight pairs so the
// per-channel loop is just: 2 loads + 4 FMA + 1 store.

struct __attribute__((packed, aligned(4))) f2u { float lo, hi; };

__global__ __launch_bounds__(256) void warp_pair(
    const float* __restrict__ img,
    const float* __restrict__ flow,
    const int* __restrict__ Hp,
    const int* __restrict__ Wp,
    float* __restrict__ out,
    int HW, int C)
{
    const int pix = blockIdx.x * blockDim.x + threadIdx.x;
    if (pix >= HW) return;

    const int W = *Wp;
    const int H = *Hp;
    const int h = pix / W;
    const int w = pix - h * W;

    const float u = flow[pix];
    const float v = flow[HW + pix];

    const float Wm1 = (float)(W - 1);
    const float Hm1 = (float)(H - 1);

    // reference's normalize/denormalize round-trip, replicated op-for-op
    float x = (float)w + u;
    float y = (float)h + v;
    x = 2.0f * (x / Wm1 - 0.5f);
    y = 2.0f * (y / Hm1 - 0.5f);
    x = (x + 1.0f) * 0.5f * Wm1;
    y = (y + 1.0f) * 0.5f * Hm1;

    const float x0 = floorf(x), x1 = x0 + 1.0f;
    const float y0 = floorf(y), y1 = y0 + 1.0f;

    const int x0c = (int)fminf(fmaxf(x0, 0.0f), Wm1);
    const int x1c = (int)fminf(fmaxf(x1, 0.0f), Wm1);
    const int y0c = (int)fminf(fmaxf(y0, 0.0f), Hm1);
    const int y1c = (int)fminf(fmaxf(y1, 0.0f), Hm1);

    // weights from UNclipped coords (reference semantics)
    const float wa = (x1 - x) * (y1 - y);
    const float wb = (x1 - x) * (y - y0);
    const float wc = (x - x0) * (y1 - y);
    const float wd = (x - x0) * (y - y0);

    // pair base column: covers {x0c, x1c} within [pb, pb+1], always in-row
    const int pb = min(x0c, W - 2);

    // fold the lo/hi element selection into the weights (handles clamps)
    const float wlo_t = (x0c == pb ? wa : 0.0f) + (x1c == pb ? wc : 0.0f);
    const float whi_t = (x0c != pb ? wa : 0.0f) + (x1c != pb ? wc : 0.0f);
    const float wlo_b = (x0c == pb ? wb : 0.0f) + (x1c == pb ? wd : 0.0f);
    const float whi_b = (x0c != pb ? wb : 0.0f) + (x1c != pb ? wd : 0.0f);

    const float* rt = img + (size_t)y0c * (size_t)W + pb;  // top row pair
    const float* rb = img + (size_t)y1c * (size_t)W + pb;  // bottom row pair
    float* po = out + pix;

    #pragma unroll 8
    for (int c = 0; c < C; ++c) {
        const size_t off = (size_t)c * (size_t)HW;
        const f2u t = *(const f2u*)(rt + off);
        const f2u b = *(const f2u*)(rb + off);
        po[off] = wlo_t * t.lo + whi_t * t.hi + wlo_b * b.lo + whi_b * b.hi;
    }
}

extern "C" void kernel_launch(void* const* d_in, const int* in_sizes, int n_in,
                              void* d_out, int out_size, void* d_ws, size_t ws_size,
                              hipStream_t stream) {
    const float* img  = (const float*)d_in[0];
    const float* flow = (const float*)d_in[1];
    const int*   Hp   = (const int*)d_in[2];
    const int*   Wp   = (const int*)d_in[3];
    float* out = (float*)d_out;

    const int HW = in_sizes[1] / 2;    // flow is (1,2,H,W)
    const int C  = in_sizes[0] / HW;   // img is (1,C,H,W)

    const int block = 256;
    const int grid  = (HW + block - 1) / block;
    warp_pair<<<grid, block, 0, stream>>>(img, flow, Hp, Wp, out, HW, C);
}

// Round 4
// 210.016 us; speedup vs baseline: 2.6965x; 1.0451x over previous
//
#include <hip/hip_runtime.h>

// Bilinear backward warp, NCHW f32.
// Wave = 16x4 pixel tile (2-D footprint shrinks distinct-cache-line count per
// gather instruction); block = 16x16 tile (4 waves). Paired-corner dwordx2
// gathers with clamp folded into weights. Bijective XCD swizzle gives each
// XCD a contiguous horizontal band of tiles for L2 locality. NT stores.

#define NTHREADS 256

struct __attribute__((packed, aligned(4))) f2u { float lo, hi; };

__global__ __launch_bounds__(NTHREADS) void warp_tile16(
    const float* __restrict__ img,
    const float* __restrict__ flow,
    const int* __restrict__ Hp,
    const int* __restrict__ Wp,
    float* __restrict__ out,
    int HW, int C)
{
    const int W = *Wp;
    const int H = *Hp;
    const int tilesX = (W + 15) >> 4;
    const int tilesY = (H + 15) >> 4;
    const int ntiles = tilesX * tilesY;

    int bid = blockIdx.x;
    if (bid >= ntiles) return;

    // bijective XCD swizzle (m204): xcd gets a contiguous chunk of row-major
    // tile ids -> a horizontal band of the image stays in one XCD's L2.
    const int q = ntiles >> 3, r = ntiles & 7;
    const int xcd = bid & 7, sub = bid >> 3;
    const int t = (xcd < r ? xcd * (q + 1) : r * (q + 1) + (xcd - r) * q) + sub;

    const int tileY = t / tilesX;
    const int tileX = t - tileY * tilesX;

    const int lane = threadIdx.x & 63;
    const int wv   = threadIdx.x >> 6;          // wave 0..3
    const int lx   = lane & 15;                 // 0..15
    const int ly   = lane >> 4;                 // 0..3

    const int gx = tileX * 16 + lx;
    const int gy = tileY * 16 + wv * 4 + ly;
    if (gx >= W || gy >= H) return;

    const int pix = gy * W + gx;

    const float u = flow[pix];
    const float v = flow[HW + pix];

    const float Wm1 = (float)(W - 1);
    const float Hm1 = (float)(H - 1);

    // reference's normalize/denormalize round-trip, replicated op-for-op
    float x = (float)gx + u;
    float y = (float)gy + v;
    x = 2.0f * (x / Wm1 - 0.5f);
    y = 2.0f * (y / Hm1 - 0.5f);
    x = (x + 1.0f) * 0.5f * Wm1;
    y = (y + 1.0f) * 0.5f * Hm1;

    const float x0 = floorf(x), x1 = x0 + 1.0f;
    const float y0 = floorf(y), y1 = y0 + 1.0f;

    const int x0c = (int)fminf(fmaxf(x0, 0.0f), Wm1);
    const int x1c = (int)fminf(fmaxf(x1, 0.0f), Wm1);
    const int y0c = (int)fminf(fmaxf(y0, 0.0f), Hm1);
    const int y1c = (int)fminf(fmaxf(y1, 0.0f), Hm1);

    // weights from UNclipped coords (reference semantics)
    const float wa = (x1 - x) * (y1 - y);
    const float wb = (x1 - x) * (y - y0);
    const float wc = (x - x0) * (y1 - y);
    const float wd = (x - x0) * (y - y0);

    // pair base column: covers {x0c, x1c} within [pb, pb+1], always in-row
    const int pb = min(x0c, W - 2);

    // fold the lo/hi selection (incl. clamp cases) into per-row weight pairs
    const float wlo_t = (x0c == pb ? wa : 0.0f) + (x1c == pb ? wc : 0.0f);
    const float whi_t = (x0c != pb ? wa : 0.0f) + (x1c != pb ? wc : 0.0f);
    const float wlo_b = (x0c == pb ? wb : 0.0f) + (x1c == pb ? wd : 0.0f);
    const float whi_b = (x0c != pb ? wb : 0.0f) + (x1c != pb ? wd : 0.0f);

    const float* rt = img + (size_t)y0c * (size_t)W + pb;  // top row pair
    const float* rb = img + (size_t)y1c * (size_t)W + pb;  // bottom row pair
    float* po = out + pix;

    #pragma unroll 8
    for (int c = 0; c < C; ++c) {
        const size_t off = (size_t)c * (size_t)HW;
        const f2u tp = *(const f2u*)(rt + off);
        const f2u bp = *(const f2u*)(rb + off);
        const float res = wlo_t * tp.lo + whi_t * tp.hi
                        + wlo_b * bp.lo + whi_b * bp.hi;
        __builtin_nontemporal_store(res, po + off);
    }
}

extern "C" void kernel_launch(void* const* d_in, const int* in_sizes, int n_in,
                              void* d_out, int out_size, void* d_ws, size_t ws_size,
                              hipStream_t stream) {
    const float* img  = (const float*)d_in[0];
    const float* flow = (const float*)d_in[1];
    const int*   Hp   = (const int*)d_in[2];
    const int*   Wp   = (const int*)d_in[3];
    float* out = (float*)d_out;

    const int HW = in_sizes[1] / 2;    // flow is (1,2,H,W)
    const int C  = in_sizes[0] / HW;   // img is (1,C,H,W)

    // exact tile count needs W,H (device-side); launch with slack, extra
    // blocks exit on the in-kernel ntiles guard.
    const int grid = (HW + 255) / 256 + 2048;
    warp_tile16<<<grid, NTHREADS, 0, stream>>>(img, flow, Hp, Wp, out, HW, C);
}

// Round 5
// 208.567 us; speedup vs baseline: 2.7153x; 1.0069x over previous
//
#include <hip/hip_runtime.h>

// Bilinear backward warp, NCHW f32.
// Wave = 16x4 pixel tile; paired-corner dwordx2 gathers with clamps folded
// into weights. Channel loop processed in batches of 16: ALL 32 gathers of a
// batch are issued before any use (maximizes loads-in-flight; we are
// latency-bound, not TA-throughput-bound). Regular stores (NT store caused
// +22% write amplification in R3). Bijective XCD band swizzle for L2 locality.

#define NTHREADS 256
#define CBATCH 16

struct __attribute__((packed, aligned(4))) f2u { float lo, hi; };

__global__ __launch_bounds__(NTHREADS) void warp_mlp(
    const float* __restrict__ img,
    const float* __restrict__ flow,
    const int* __restrict__ Hp,
    const int* __restrict__ Wp,
    float* __restrict__ out,
    int HW, int C)
{
    const int W = *Wp;
    const int H = *Hp;
    const int tilesX = (W + 15) >> 4;
    const int tilesY = (H + 15) >> 4;
    const int ntiles = tilesX * tilesY;

    const int bid = blockIdx.x;
    if (bid >= ntiles) return;

    // bijective XCD swizzle: each XCD gets a contiguous band of tile ids
    const int q = ntiles >> 3, r = ntiles & 7;
    const int xcd = bid & 7, sub = bid >> 3;
    const int t = (xcd < r ? xcd * (q + 1) : r * (q + 1) + (xcd - r) * q) + sub;

    const int tileY = t / tilesX;
    const int tileX = t - tileY * tilesX;

    const int lane = threadIdx.x & 63;
    const int wv   = threadIdx.x >> 6;
    const int lx   = lane & 15;
    const int ly   = lane >> 4;

    const int gx = tileX * 16 + lx;
    const int gy = tileY * 16 + wv * 4 + ly;
    if (gx >= W || gy >= H) return;

    const int pix = gy * W + gx;

    const float u = flow[pix];
    const float v = flow[HW + pix];

    const float Wm1 = (float)(W - 1);
    const float Hm1 = (float)(H - 1);

    // reference's normalize/denormalize round-trip, replicated op-for-op
    float x = (float)gx + u;
    float y = (float)gy + v;
    x = 2.0f * (x / Wm1 - 0.5f);
    y = 2.0f * (y / Hm1 - 0.5f);
    x = (x + 1.0f) * 0.5f * Wm1;
    y = (y + 1.0f) * 0.5f * Hm1;

    const float x0 = floorf(x), x1 = x0 + 1.0f;
    const float y0 = floorf(y), y1 = y0 + 1.0f;

    const int x0c = (int)fminf(fmaxf(x0, 0.0f), Wm1);
    const int x1c = (int)fminf(fmaxf(x1, 0.0f), Wm1);
    const int y0c = (int)fminf(fmaxf(y0, 0.0f), Hm1);
    const int y1c = (int)fminf(fmaxf(y1, 0.0f), Hm1);

    // weights from UNclipped coords (reference semantics)
    const float wa = (x1 - x) * (y1 - y);
    const float wb = (x1 - x) * (y - y0);
    const float wc = (x - x0) * (y1 - y);
    const float wd = (x - x0) * (y - y0);

    // pair base column: covers {x0c, x1c} within [pb, pb+1]
    const int pb = min(x0c, W - 2);

    // fold lo/hi selection (incl. clamps) into per-row weight pairs
    const float wlo_t = (x0c == pb ? wa : 0.0f) + (x1c == pb ? wc : 0.0f);
    const float whi_t = (x0c != pb ? wa : 0.0f) + (x1c != pb ? wc : 0.0f);
    const float wlo_b = (x0c == pb ? wb : 0.0f) + (x1c == pb ? wd : 0.0f);
    const float whi_b = (x0c != pb ? wb : 0.0f) + (x1c != pb ? wd : 0.0f);

    const float* rt = img + (size_t)y0c * (size_t)W + pb;
    const float* rb = img + (size_t)y1c * (size_t)W + pb;
    float* po = out + pix;

    // channel loop in batches: issue all loads of the batch, then compute.
    for (int c0 = 0; c0 < C; c0 += CBATCH) {
        f2u tp[CBATCH], bp[CBATCH];
        #pragma unroll
        for (int k = 0; k < CBATCH; ++k) {
            const size_t off = (size_t)(c0 + k) * (size_t)HW;
            tp[k] = *(const f2u*)(rt + off);
            bp[k] = *(const f2u*)(rb + off);
        }
        #pragma unroll
        for (int k = 0; k < CBATCH; ++k) {
            const size_t off = (size_t)(c0 + k) * (size_t)HW;
            po[off] = wlo_t * tp[k].lo + whi_t * tp[k].hi
                    + wlo_b * bp[k].lo + whi_b * bp[k].hi;
        }
    }
}

extern "C" void kernel_launch(void* const* d_in, const int* in_sizes, int n_in,
                              void* d_out, int out_size, void* d_ws, size_t ws_size,
                              hipStream_t stream) {
    const float* img  = (const float*)d_in[0];
    const float* flow = (const float*)d_in[1];
    const int*   Hp   = (const int*)d_in[2];
    const int*   Wp   = (const int*)d_in[3];
    float* out = (float*)d_out;

    const int HW = in_sizes[1] / 2;    // flow is (1,2,H,W)
    const int C  = in_sizes[0] / HW;   // img is (1,C,H,W)

    const int grid = (HW + 255) / 256 + 2048;  // slack; extras exit on guard
    warp_mlp<<<grid, NTHREADS, 0, stream>>>(img, flow, Hp, Wp, out, HW, C);
}